// Round 16
// baseline (162.791 us; speedup 1.0000x reference)
//
#include <hip/hip_runtime.h>
#include <math.h>

#define NPTS 524288
#define EDIM 16
#define RES  128
#define HDIM 128
#define DIN  19
#define OXs  (RES*RES*EDIM)
#define OYs  (RES*EDIM)
#define OZs  (EDIM)
#define NBLK 256
#define NWAVE 12                      // 768 threads = 12 waves = 3 waves/SIMD
#define BATCH (NWAVE * 16)            // 192 points per block-iteration
#define NITER 11                      // ceil(ceil(NPTS/192)/NBLK)

typedef _Float16 f16;
typedef __attribute__((ext_vector_type(8))) _Float16 f16x8;
typedef __attribute__((ext_vector_type(4))) float f32x4;

// ---- d_ws byte layout (fp16 packs in exact MFMA B-frag order) ----
#define WS_P1 0        // GEMM1 B: W1T   [8nt][4t][64l][8e]  32768B
#define WS_P2 32768    // GEMM2 B: W1    [8nt][4t][64l][8e]  32768B
#define WS_P0 65536    // GEMM0 B: W0T emb rows [8nt][64l][8e] 8192B
#define WS_P3 73728    // GEMM3 B: W0    [2nt][4t][64l][8e]  8192B
#define WS_T  81920    // tables f32: W0[:,16],W0[:,17],W0[:,18],b0,b1,Wo (6x128) 3072B
#define WS_BYTES 84992

// Same-wave DS RAW ordering: LDS ops from one wave execute in order, so a
// wave-private bounce needs only COMPILE-TIME ordering (no runtime drain).
#define DS_ORDER() asm volatile("" ::: "memory")

// ---------------------------------------------------------------------------
// Prep: pack weights into MFMA fragment order.
// Frag maps (16x16x32, c=l&15, g=l>>4):
//   A[row][k]  : lane l elem e -> A[c][8g+e]
//   B[k][col]  : lane l elem e -> B[8g+e][c]
//   D[row][col]: lane l reg  r -> D[4g+r][c]
// ---------------------------------------------------------------------------
__global__ void pack_weights(const float* __restrict__ W0, const float* __restrict__ b0,
                             const float* __restrict__ W1, const float* __restrict__ b1,
                             const float* __restrict__ Wo, unsigned char* __restrict__ ws) {
    int idx = blockIdx.x * 256 + threadIdx.x;
    f16* p1 = (f16*)(ws + WS_P1);
    f16* p2 = (f16*)(ws + WS_P2);
    f16* p0 = (f16*)(ws + WS_P0);
    f16* p3 = (f16*)(ws + WS_P3);
    float* tb = (float*)(ws + WS_T);
    if (idx < 16384) {                       // PACK1: B=W1T -> elem = W1[c+16nt][8g+e+32t]
        int e = idx & 7, l = (idx >> 3) & 63, t = (idx >> 9) & 3, nt = idx >> 11;
        int c = l & 15, g = l >> 4;
        p1[idx] = (f16)W1[(c + 16*nt)*HDIM + (8*g + e + 32*t)];
    } else if (idx < 32768) {                // PACK2: B=W1  -> elem = W1[8g+e+32t][c+16nt]
        int i = idx - 16384;
        int e = i & 7, l = (i >> 3) & 63, t = (i >> 9) & 3, nt = i >> 11;
        int c = l & 15, g = l >> 4;
        p2[i] = (f16)W1[(8*g + e + 32*t)*HDIM + (c + 16*nt)];
    } else if (idx < 36864) {                // PACK0: B=W0T emb rows (k=d<16 real, else 0)
        int i = idx - 32768;
        int e = i & 7, l = (i >> 3) & 63, nt = i >> 9;
        int c = l & 15, g = l >> 4;
        int d = 8*g + e;
        p0[i] = (d < EDIM) ? (f16)W0[(c + 16*nt)*DIN + d] : (f16)0.f;
    } else if (idx < 40960) {                // PACK3: B=W0 (col=din<19 real, else 0)
        int i = idx - 36864;
        int e = i & 7, l = (i >> 3) & 63, t = (i >> 9) & 3, nt = i >> 11;
        int c = l & 15, g = l >> 4;
        int din = c + 16*nt;
        p3[i] = (din < DIN) ? (f16)W0[(8*g + e + 32*t)*DIN + din] : (f16)0.f;
    } else if (idx < 41728) {                // tables
        int i = idx - 40960;
        int j = i & 127, sel = i >> 7;
        float v;
        if (sel == 0)      v = W0[j*DIN + 16];
        else if (sel == 1) v = W0[j*DIN + 17];
        else if (sel == 2) v = W0[j*DIN + 18];
        else if (sel == 3) v = b0[j];
        else if (sel == 4) v = b1[j];
        else               v = Wo[j];
        tb[i] = v;
    }
}

// ---------------------------------------------------------------------------
// Persistent fused kernel. 256 blocks (1/CU) x 768 thr (12 waves =
// 3 waves/SIMD; LDS 133376 B caps at 1 block/CU anyway).
// r15 prefetch structure + amdgpu_waves_per_eu(1,3): tells the allocator
// the LDS-imposed truth (max 3 waves/EU), raising the VGPR budget to ~170
// so the carried prefetch state fits in registers instead of spilling.
// (r15 diagnosis: allocator pinned 84 VGPR = 6-wave target that LDS makes
// impossible, and spilled 37 MB of scratch. launch_bounds' 2nd arg can't
// express a MAX — r3/r6/r8 proved raising the MIN collapses VGPR to 64.)
// SPILL TRIPWIRE: WRITE_SIZE >> 8.6 MB or VGPR still 84 -> revert to r14.
// ---------------------------------------------------------------------------
__global__ __launch_bounds__(768)
__attribute__((amdgpu_waves_per_eu(1, 3)))
void sdf_mfma(const float* __restrict__ pos,
              const float* __restrict__ gridp,
              const unsigned char* __restrict__ ws,
              const float* __restrict__ bo,
              float* __restrict__ out) {
    __shared__ f16 sP1[16384];
    __shared__ f16 sP2[16384];
    __shared__ f16 sP0[4096];
    __shared__ f16 sP3[4096];
    __shared__ float sT[768];
    __shared__ unsigned char sBounce[NWAVE][4352];   // per-wave: 16 rows x 136 f16

    const int tid = threadIdx.x;
    // ---- stage packs to LDS (once per block; 768 threads) ----
    {
        const uint4* src = (const uint4*)ws;
        uint4* d1 = (uint4*)sP1;
        uint4* d2 = (uint4*)sP2;
        uint4* d0 = (uint4*)sP0;
        uint4* d3 = (uint4*)sP3;
        uint4* dt = (uint4*)sT;
#pragma unroll
        for (int i = 0; i < 3; ++i) {
            int k = tid + i * 768;
            if (k < 2048) { d1[k] = src[k]; d2[k] = src[2048 + k]; }
        }
        if (tid < 512) { d0[tid] = src[4096 + tid]; d3[tid] = src[4608 + tid]; }
        if (tid < 192) dt[tid] = src[5120 + tid];
    }
    __syncthreads();

    const int l = tid & 63, w = tid >> 6;
    const int c = l & 15, g = l >> 4;
    const int s = g & 1, q = g >> 1;     // gather: slice s, corner-quad q

    f16* sBW = (f16*)sBounce[w];
    const f16x8* P0 = (const f16x8*)sP0;
    const f16x8* P1 = (const f16x8*)sP1;
    const f16x8* P2 = (const f16x8*)sP2;
    const f16x8* P3 = (const f16x8*)sP3;
    const f32x4 z4 = {0.f, 0.f, 0.f, 0.f};
    const float bov = bo[0];

    // ---- carried prefetch state (it=0 prologue) ----
    float cf0, cf1, cf2;
    const float* cgb;
    float4 cd[8];
    {
        const int npbase = blockIdx.x * NITER * BATCH + w * 16;
        const int npt = (npbase < NPTS) ? npbase + c : c;
        const float ppx = fmaf(pos[3*npt+0], 0.5f, 0.5f);
        const float ppy = fmaf(pos[3*npt+1], 0.5f, 0.5f);
        const float ppz = fmaf(pos[3*npt+2], 0.5f, 0.5f);
        const float x0 = ppx*127.f, x1 = ppy*127.f, x2 = ppz*127.f;
        int i0 = (int)floorf(x0); i0 = i0 < 0 ? 0 : (i0 > 126 ? 126 : i0);
        int i1 = (int)floorf(x1); i1 = i1 < 0 ? 0 : (i1 > 126 ? 126 : i1);
        int i2 = (int)floorf(x2); i2 = i2 < 0 ? 0 : (i2 > 126 ? 126 : i2);
        cf0 = x0 - (float)i0; cf1 = x1 - (float)i1; cf2 = x2 - (float)i2;
        cgb = gridp + (size_t)((i0*RES + i1)*RES + i2)*EDIM;
#pragma unroll
        for (int j = 0; j < 4; ++j) {
            const float* gp = cgb + q*OXs + ((j>>1)&1)*OYs + (j&1)*OZs + 8*s;
            cd[2*j]   = *(const float4*)gp;
            cd[2*j+1] = *(const float4*)(gp + 4);
        }
    }

#pragma unroll 1
    for (int it = 0; it < NITER; ++it) {
        const int pbase = (blockIdx.x * NITER + it) * BATCH + w * 16;
        if (pbase >= NPTS) continue;          // wave-uniform tail skip
        const int pt = pbase + c;

        // ---- trilinear weights from carried (prefetched) state ----
        const float f0 = cf0, f1 = cf1, f2 = cf2;
        const float wx1 = f0, wx0 = 1.f - f0;
        const float wy1 = f1, wy0 = 1.f - f1;
        const float wz1 = f2, wz0 = 1.f - f2;
        const float* gb = cgb;

        // ---- ALL-LANE gather from PREFETCHED registers (no mem latency) ----
        float w8[8] = {0.f,0.f,0.f,0.f,0.f,0.f,0.f,0.f};
        {
            const float wxq = q ? wx1 : wx0;
#pragma unroll
            for (int j = 0; j < 4; ++j) {
                const float4 qa = cd[2*j];
                const float4 qb = cd[2*j + 1];
                const float wc = wxq * ((j&2)?wy1:wy0) * ((j&1)?wz1:wz0);
                w8[0] = fmaf(wc, qa.x, w8[0]);  w8[1] = fmaf(wc, qa.y, w8[1]);
                w8[2] = fmaf(wc, qa.z, w8[2]);  w8[3] = fmaf(wc, qa.w, w8[3]);
                w8[4] = fmaf(wc, qb.x, w8[4]);  w8[5] = fmaf(wc, qb.y, w8[5]);
                w8[6] = fmaf(wc, qb.z, w8[6]);  w8[7] = fmaf(wc, qb.w, w8[7]);
            }
        }
        // combine corner-quads: partner lane is lane^32 (g^2)
        f16x8 afe;
#pragma unroll
        for (int m = 0; m < 8; ++m) {
            const float full = w8[m] + __shfl_xor(w8[m], 32);
            afe[m] = (g < 2) ? (f16)full : (f16)0.f;
        }

        // ---- GEMM0: a0 emb part ----
        f32x4 acc[8];
        __builtin_amdgcn_s_setprio(1);
#pragma unroll
        for (int nt = 0; nt < 8; ++nt)
            acc[nt] = __builtin_amdgcn_mfma_f32_16x16x32_f16(afe, P0[nt*64 + l], z4, 0, 0, 0);
        __builtin_amdgcn_s_setprio(0);

        // ---- pos/bias fold (exact fp32), t0 = 30*a0, h1 -> bounce ----
        float rpx[4], rpy[4], rpz[4];
        {
            const float* pp = pos + 3 * (pbase + 4*g);
            const float4 fa = *(const float4*)(pp + 0);
            const float4 fb = *(const float4*)(pp + 4);
            const float4 fc = *(const float4*)(pp + 8);
            rpx[0] = fmaf(fa.x, 0.5f, 0.5f); rpy[0] = fmaf(fa.y, 0.5f, 0.5f); rpz[0] = fmaf(fa.z, 0.5f, 0.5f);
            rpx[1] = fmaf(fa.w, 0.5f, 0.5f); rpy[1] = fmaf(fb.x, 0.5f, 0.5f); rpz[1] = fmaf(fb.y, 0.5f, 0.5f);
            rpx[2] = fmaf(fb.z, 0.5f, 0.5f); rpy[2] = fmaf(fb.w, 0.5f, 0.5f); rpz[2] = fmaf(fc.x, 0.5f, 0.5f);
            rpx[3] = fmaf(fc.y, 0.5f, 0.5f); rpy[3] = fmaf(fc.z, 0.5f, 0.5f); rpz[3] = fmaf(fc.w, 0.5f, 0.5f);
        }
        float t0a[8][4];
#pragma unroll
        for (int nt = 0; nt < 8; ++nt) {
            const int j = c + 16*nt;
            const float t16 = sT[j], t17 = sT[128+j], t18 = sT[256+j], tb0 = sT[384+j];
#pragma unroll
            for (int r = 0; r < 4; ++r) {
                float a0 = acc[nt][r] + tb0;
                a0 = fmaf(rpx[r], t16, a0);
                a0 = fmaf(rpy[r], t17, a0);
                a0 = fmaf(rpz[r], t18, a0);
                const float t0 = 30.f * a0;
                t0a[nt][r] = t0;
                sBW[(4*g + r)*136 + j] = (f16)__sinf(t0);
            }
        }
        DS_ORDER();   // same-wave DS in-order: no runtime drain needed

        // ---- GEMM1: a1 = h1 @ W1T ----
        f16x8 af[4];
#pragma unroll
        for (int t = 0; t < 4; ++t)
            af[t] = *(const f16x8*)&sBW[c*136 + 32*t + 8*g];
        __builtin_amdgcn_s_setprio(1);
#pragma unroll
        for (int nt = 0; nt < 8; ++nt) {
            f32x4 a = z4;
#pragma unroll
            for (int t = 0; t < 4; ++t)
                a = __builtin_amdgcn_mfma_f32_16x16x32_f16(af[t], P1[(nt*4+t)*64 + l], a, 0, 0, 0);
            acc[nt] = a;
        }
        __builtin_amdgcn_s_setprio(0);

        // ---- mid: sdf partial + da1 -> bounce ----
        float sp[4] = {0.f, 0.f, 0.f, 0.f};
#pragma unroll
        for (int nt = 0; nt < 8; ++nt) {
            const int j = c + 16*nt;
            const float b1j = sT[512+j], woj = sT[640+j];
#pragma unroll
            for (int r = 0; r < 4; ++r) {
                const float t1 = 30.f * (acc[nt][r] + b1j);
                sp[r] = fmaf(woj, __sinf(t1), sp[r]);
                sBW[(4*g + r)*136 + j] = (f16)(30.f * woj * __cosf(t1));
            }
        }
        // sdf reduce over c-lanes and store
#pragma unroll
        for (int r = 0; r < 4; ++r) {
            sp[r] += __shfl_xor(sp[r], 1);
            sp[r] += __shfl_xor(sp[r], 2);
            sp[r] += __shfl_xor(sp[r], 4);
            sp[r] += __shfl_xor(sp[r], 8);
        }
        if (c == 0) {
#pragma unroll
            for (int r = 0; r < 4; ++r) out[pbase + 4*g + r] = sp[r] + bov;
        }
        DS_ORDER();

        // ---- hoist grad-combine corner loads (L1-hot: same lines as gather) ----
        float4 ca[2][4];
#pragma unroll
        for (int h = 0; h < 2; ++h) {
            const int cr = 2*g + h;
            const float* gp = gb + ((cr>>2)&1)*OXs + ((cr>>1)&1)*OYs + (cr&1)*OZs;
            ca[h][0] = *(const float4*)gp;
            ca[h][1] = *(const float4*)(gp + 4);
            ca[h][2] = *(const float4*)(gp + 8);
            ca[h][3] = *(const float4*)(gp + 12);
        }

        // ---- PREFETCH it+1: pos -> fractions -> gb -> 8 corner float4s ----
        // (hidden under GEMM2 / da0 / GEMM3 / grad phases)
        float nf0, nf1, nf2;
        const float* ngbp;
        float4 ncd[8];
        {
            const int nb = (blockIdx.x * NITER + (it + 1)) * BATCH + w * 16;
            const int npt = (nb < NPTS) ? nb + c : c;
            const float ppx = fmaf(pos[3*npt+0], 0.5f, 0.5f);
            const float ppy = fmaf(pos[3*npt+1], 0.5f, 0.5f);
            const float ppz = fmaf(pos[3*npt+2], 0.5f, 0.5f);
            const float x0 = ppx*127.f, x1 = ppy*127.f, x2 = ppz*127.f;
            int i0 = (int)floorf(x0); i0 = i0 < 0 ? 0 : (i0 > 126 ? 126 : i0);
            int i1 = (int)floorf(x1); i1 = i1 < 0 ? 0 : (i1 > 126 ? 126 : i1);
            int i2 = (int)floorf(x2); i2 = i2 < 0 ? 0 : (i2 > 126 ? 126 : i2);
            nf0 = x0 - (float)i0; nf1 = x1 - (float)i1; nf2 = x2 - (float)i2;
            ngbp = gridp + (size_t)((i0*RES + i1)*RES + i2)*EDIM;
#pragma unroll
            for (int j = 0; j < 4; ++j) {
                const float* gp = ngbp + q*OXs + ((j>>1)&1)*OYs + (j&1)*OZs + 8*s;
                ncd[2*j]   = *(const float4*)gp;
                ncd[2*j+1] = *(const float4*)(gp + 4);
            }
        }

        // ---- GEMM2: dh1 = da1 @ W1 ----
#pragma unroll
        for (int t = 0; t < 4; ++t)
            af[t] = *(const f16x8*)&sBW[c*136 + 32*t + 8*g];
        __builtin_amdgcn_s_setprio(1);
#pragma unroll
        for (int nt = 0; nt < 8; ++nt) {
            f32x4 a = z4;
#pragma unroll
            for (int t = 0; t < 4; ++t)
                a = __builtin_amdgcn_mfma_f32_16x16x32_f16(af[t], P2[(nt*4+t)*64 + l], a, 0, 0, 0);
            acc[nt] = a;
        }
        __builtin_amdgcn_s_setprio(0);

        // ---- da0 = dh1 * 30*cos(t0) -> bounce ----
#pragma unroll
        for (int nt = 0; nt < 8; ++nt) {
            const int k = c + 16*nt;
#pragma unroll
            for (int r = 0; r < 4; ++r) {
                const float da0 = acc[nt][r] * (30.f * __cosf(t0a[nt][r]));
                sBW[(4*g + r)*136 + k] = (f16)da0;
            }
        }
        DS_ORDER();

        // ---- GEMM3: dv = da0 @ W0 ----
#pragma unroll
        for (int t = 0; t < 4; ++t)
            af[t] = *(const f16x8*)&sBW[c*136 + 32*t + 8*g];
        f32x4 d3a = z4, d3b = z4;
        __builtin_amdgcn_s_setprio(1);
#pragma unroll
        for (int t = 0; t < 4; ++t) {
            d3a = __builtin_amdgcn_mfma_f32_16x16x32_f16(af[t], P3[t*64 + l],     d3a, 0, 0, 0);
            d3b = __builtin_amdgcn_mfma_f32_16x16x32_f16(af[t], P3[(4+t)*64 + l], d3b, 0, 0, 0);
        }
        __builtin_amdgcn_s_setprio(0);

        // ---- dv -> LDS (reuse bounce region as fp32 [16][20]) ----
        float* sDV = (float*)sBounce[w];
#pragma unroll
        for (int r = 0; r < 4; ++r) sDV[(4*g + r)*20 + c] = d3a[r];
        if (c < 3) {
#pragma unroll
            for (int r = 0; r < 4; ++r) sDV[(4*g + r)*20 + 16 + c] = d3b[r];
        }
        DS_ORDER();

        // ---- gradient combine: lane (c,g) does corners 2g, 2g+1 of point c ----
        const f32x4 dva = *(const f32x4*)&sDV[c*20 + 0];
        const f32x4 dvb = *(const f32x4*)&sDV[c*20 + 4];
        const f32x4 dvc = *(const f32x4*)&sDV[c*20 + 8];
        const f32x4 dvd = *(const f32x4*)&sDV[c*20 + 12];
        float scv[2];
#pragma unroll
        for (int h = 0; h < 2; ++h) {
            float sdot = ca[h][0].x*dva[0] + ca[h][0].y*dva[1] + ca[h][0].z*dva[2] + ca[h][0].w*dva[3]
                       + ca[h][1].x*dvb[0] + ca[h][1].y*dvb[1] + ca[h][1].z*dvb[2] + ca[h][1].w*dvb[3]
                       + ca[h][2].x*dvc[0] + ca[h][2].y*dvc[1] + ca[h][2].z*dvc[2] + ca[h][2].w*dvc[3]
                       + ca[h][3].x*dvd[0] + ca[h][3].y*dvd[1] + ca[h][3].z*dvd[2] + ca[h][3].w*dvd[3];
            scv[h] = sdot;
        }
        float* sSC = (float*)sBounce[w] + 320;   // 16 x 8 f32
        sSC[c*8 + 2*g]     = scv[0];
        sSC[c*8 + 2*g + 1] = scv[1];
        DS_ORDER();
        if (g == 0) {
            const float* scp = &sSC[c*8];
            const float sc0 = scp[0], sc1 = scp[1], sc2 = scp[2], sc3 = scp[3];
            const float sc4 = scp[4], sc5 = scp[5], sc6 = scp[6], sc7 = scp[7];
            const float gx = 127.f * (wy0*wz0*(sc4-sc0) + wy0*wz1*(sc5-sc1) +
                                      wy1*wz0*(sc6-sc2) + wy1*wz1*(sc7-sc3));
            const float gy = 127.f * (wx0*wz0*(sc2-sc0) + wx0*wz1*(sc3-sc1) +
                                      wx1*wz0*(sc6-sc4) + wx1*wz1*(sc7-sc5));
            const float gz = 127.f * (wx0*wy0*(sc1-sc0) + wx0*wy1*(sc3-sc2) +
                                      wx1*wy0*(sc5-sc4) + wx1*wy1*(sc7-sc6));
            out[NPTS + 3*pt + 0] = gx + sDV[c*20 + 16];
            out[NPTS + 3*pt + 1] = gy + sDV[c*20 + 17];
            out[NPTS + 3*pt + 2] = gz + sDV[c*20 + 18];
        }
        DS_ORDER();

        // ---- rotate carried prefetch state ----
        cf0 = nf0; cf1 = nf1; cf2 = nf2; cgb = ngbp;
#pragma unroll
        for (int j = 0; j < 8; ++j) cd[j] = ncd[j];
    }
}

// ===========================================================================
// Fallback (round-2 proven VALU path) — used only if ws_size < WS_BYTES.
// ===========================================================================
#define JCHUNK 64
__global__ void transpose_w1(const float* __restrict__ W1, float* __restrict__ W1T) {
    int idx = blockIdx.x * 256 + threadIdx.x;
    if (idx < HDIM * HDIM) {
        int j = idx >> 7, k = idx & 127;
        W1T[k * HDIM + j] = W1[j * HDIM + k];
    }
}
#define LOAD16(gq)                                   \
    float4 q0 = *(const float4*)((gq) + 0);          \
    float4 q1 = *(const float4*)((gq) + 4);          \
    float4 q2 = *(const float4*)((gq) + 8);          \
    float4 q3 = *(const float4*)((gq) + 12);

template<int RS, int CS>
__global__ __launch_bounds__(256, 2)
void sdf_fused(const float* __restrict__ pos, const float* __restrict__ gridp,
               const float* __restrict__ W0, const float* __restrict__ b0,
               const float* __restrict__ W1m, const float* __restrict__ b1,
               const float* __restrict__ Wo, const float* __restrict__ bo,
               float* __restrict__ out) {
    const int i = blockIdx.x * 256 + threadIdx.x;
    if (i >= NPTS) return;
    const float W0S = 30.0f;
    const float px = fmaf(pos[3*i+0], 0.5f, 0.5f);
    const float py = fmaf(pos[3*i+1], 0.5f, 0.5f);
    const float pz = fmaf(pos[3*i+2], 0.5f, 0.5f);
    const float x0 = px*127.f, x1 = py*127.f, x2 = pz*127.f;
    int i0 = (int)floorf(x0); i0 = i0 < 0 ? 0 : (i0 > 126 ? 126 : i0);
    int i1 = (int)floorf(x1); i1 = i1 < 0 ? 0 : (i1 > 126 ? 126 : i1);
    int i2 = (int)floorf(x2); i2 = i2 < 0 ? 0 : (i2 > 126 ? 126 : i2);
    const float f0 = x0-(float)i0, f1 = x1-(float)i1, f2 = x2-(float)i2;
    const float wx1 = f0, wx0 = 1.f-f0, wy1 = f1, wy0 = 1.f-f1, wz1 = f2, wz0 = 1.f-f2;
    const float* gb = gridp + (size_t)((i0*RES+i1)*RES+i2)*EDIM;
    float cw[8];
    cw[0]=wx0*wy0*wz0; cw[1]=wx0*wy0*wz1; cw[2]=wx0*wy1*wz0; cw[3]=wx0*wy1*wz1;
    cw[4]=wx1*wy0*wz0; cw[5]=wx1*wy0*wz1; cw[6]=wx1*wy1*wz0; cw[7]=wx1*wy1*wz1;
    float v[DIN];
#pragma unroll
    for (int e = 0; e < EDIM; ++e) v[e] = 0.f;
#pragma unroll
    for (int cr = 0; cr < 8; ++cr) {
        const float* gq = gb + ((cr>>2)&1)*OXs + ((cr>>1)&1)*OYs + (cr&1)*OZs;
        LOAD16(gq);
        const float wc = cw[cr];
        v[0]=fmaf(wc,q0.x,v[0]); v[1]=fmaf(wc,q0.y,v[1]); v[2]=fmaf(wc,q0.z,v[2]); v[3]=fmaf(wc,q0.w,v[3]);
        v[4]=fmaf(wc,q1.x,v[4]); v[5]=fmaf(wc,q1.y,v[5]); v[6]=fmaf(wc,q1.z,v[6]); v[7]=fmaf(wc,q1.w,v[7]);
        v[8]=fmaf(wc,q2.x,v[8]); v[9]=fmaf(wc,q2.y,v[9]); v[10]=fmaf(wc,q2.z,v[10]); v[11]=fmaf(wc,q2.w,v[11]);
        v[12]=fmaf(wc,q3.x,v[12]); v[13]=fmaf(wc,q3.y,v[13]); v[14]=fmaf(wc,q3.z,v[14]); v[15]=fmaf(wc,q3.w,v[15]);
    }
    v[16]=px; v[17]=py; v[18]=pz;
    float dv[DIN];
#pragma unroll
    for (int m = 0; m < DIN; ++m) dv[m] = 0.f;
    float sdf = bo[0];
#pragma unroll 1
    for (int cch = 0; cch < HDIM/JCHUNK; ++cch) {
        const int j0 = cch * JCHUNK;
        float a1c[JCHUNK];
#pragma unroll
        for (int jj = 0; jj < JCHUNK; ++jj) a1c[jj] = 0.f;
#pragma unroll 1
    for (int k = 0; k < HDIM; ++k) {
            float a0 = b0[k];
            const float* w0r = W0 + k*DIN;
#pragma unroll
            for (int m = 0; m < DIN; ++m) a0 = fmaf(w0r[m], v[m], a0);
            const float h1 = __sinf(W0S*a0);
            const float* wr = W1m + k*RS + j0*CS;
#pragma unroll
            for (int jj = 0; jj < JCHUNK; ++jj) a1c[jj] = fmaf(wr[jj*CS], h1, a1c[jj]);
        }
#pragma unroll
        for (int jj = 0; jj < JCHUNK; ++jj) {
            const float t = W0S*(a1c[jj] + b1[j0+jj]);
            float sv, co; __sincosf(t, &sv, &co);
            const float wo = Wo[j0+jj];
            sdf = fmaf(wo, sv, sdf);
            a1c[jj] = (W0S*wo)*co;
        }
#pragma unroll 1
        for (int k = 0; k < HDIM; ++k) {
            const float* wr = W1m + k*RS + j0*CS;
            float s0=0.f,s1=0.f,s2=0.f,s3=0.f;
#pragma unroll
            for (int jj = 0; jj < JCHUNK; jj += 4) {
                s0 = fmaf(wr[(jj+0)*CS], a1c[jj+0], s0);
                s1 = fmaf(wr[(jj+1)*CS], a1c[jj+1], s1);
                s2 = fmaf(wr[(jj+2)*CS], a1c[jj+2], s2);
                s3 = fmaf(wr[(jj+3)*CS], a1c[jj+3], s3);
            }
            const float dh1 = (s0+s1)+(s2+s3);
            float a0 = b0[k];
            const float* w0r = W0 + k*DIN;
#pragma unroll
            for (int m = 0; m < DIN; ++m) a0 = fmaf(w0r[m], v[m], a0);
            const float da0 = dh1 * W0S * __cosf(W0S*a0);
#pragma unroll
            for (int m = 0; m < DIN; ++m) dv[m] = fmaf(w0r[m], da0, dv[m]);
        }
    }
    float sc[8];
#pragma unroll
    for (int cr = 0; cr < 8; ++cr) {
        const float* gq = gb + ((cr>>2)&1)*OXs + ((cr>>1)&1)*OYs + (cr&1)*OZs;
        LOAD16(gq);
        float t0 = q0.x*dv[0]+q0.y*dv[1]+q0.z*dv[2]+q0.w*dv[3];
        float t1 = q1.x*dv[4]+q1.y*dv[5]+q1.z*dv[6]+q1.w*dv[7];
        float t2 = q2.x*dv[8]+q2.y*dv[9]+q2.z*dv[10]+q2.w*dv[11];
        float t3 = q3.x*dv[12]+q3.y*dv[13]+q3.z*dv[14]+q3.w*dv[15];
        sc[cr] = (t0+t1)+(t2+t3);
    }
    const float gx = 127.f*(wy0*wz0*(sc[4]-sc[0]) + wy0*wz1*(sc[5]-sc[1]) + wy1*wz0*(sc[6]-sc[2]) + wy1*wz1*(sc[7]-sc[3]));
    const float gy = 127.f*(wx0*wz0*(sc[2]-sc[0]) + wx0*wz1*(sc[3]-sc[1]) + wx1*wz0*(sc[6]-sc[4]) + wx1*wz1*(sc[7]-sc[5]));
    const float gz = 127.f*(wx0*wy0*(sc[1]-sc[0]) + wx0*wy1*(sc[3]-sc[2]) + wx1*wy0*(sc[5]-sc[4]) + wx1*wy1*(sc[7]-sc[6]));
    out[i] = sdf;
    out[NPTS + 3*i + 0] = gx + dv[16];
    out[NPTS + 3*i + 1] = gy + dv[17];
    out[NPTS + 3*i + 2] = gz + dv[18];
}

// ---------------------------------------------------------------------------
extern "C" void kernel_launch(void* const* d_in, const int* in_sizes, int n_in,
                              void* d_out, int out_size, void* d_ws, size_t ws_size,
                              hipStream_t stream) {
    const float* pos  = (const float*)d_in[0];
    const float* grid = (const float*)d_in[1];
    const float* W0   = (const float*)d_in[2];
    const float* b0   = (const float*)d_in[3];
    const float* W1   = (const float*)d_in[4];
    const float* b1   = (const float*)d_in[5];
    const float* Wo   = (const float*)d_in[6];
    const float* bo   = (const float*)d_in[7];
    float* out = (float*)d_out;

    if (ws_size >= (size_t)WS_BYTES) {
        pack_weights<<<(41728 + 255)/256, 256, 0, stream>>>(W0, b0, W1, b1, Wo, (unsigned char*)d_ws);
        sdf_mfma<<<NBLK, 768, 0, stream>>>(pos, grid, (const unsigned char*)d_ws, bo, out);
    } else if (ws_size >= (size_t)(HDIM*HDIM*sizeof(float))) {
        float* W1T = (float*)d_ws;
        transpose_w1<<<(HDIM*HDIM + 255)/256, 256, 0, stream>>>(W1, W1T);
        sdf_fused<HDIM, 1><<<NPTS/256, 256, 0, stream>>>(pos, grid, W0, b0, W1T, b1, Wo, bo, out);
    } else {
        sdf_fused<1, HDIM><<<NPTS/256, 256, 0, stream>>>(pos, grid, W0, b0, W1, b1, Wo, bo, out);
    }
}

// Round 17
// 112.130 us; speedup vs baseline: 1.4518x; 1.4518x over previous
//
#include <hip/hip_runtime.h>
#include <math.h>

#define NPTS 524288
#define EDIM 16
#define RES  128
#define HDIM 128
#define DIN  19
#define OXs  (RES*RES*EDIM)
#define OYs  (RES*EDIM)
#define OZs  (EDIM)
#define NBLK 256
#define NWAVE 12                      // 768 threads = 12 waves = 3 waves/SIMD
#define BATCH (NWAVE * 16)            // 192 points per block-iteration
#define NITER 11                      // ceil(ceil(NPTS/192)/NBLK)

typedef _Float16 f16;
typedef __attribute__((ext_vector_type(8))) _Float16 f16x8;
typedef __attribute__((ext_vector_type(4))) float f32x4;

// ---- d_ws byte layout (fp16 packs in exact MFMA B-frag order) ----
#define WS_P1 0        // GEMM1 B: W1T   [8nt][4t][64l][8e]  32768B
#define WS_P2 32768    // GEMM2 B: W1    [8nt][4t][64l][8e]  32768B
#define WS_P0 65536    // GEMM0 B: W0T emb rows [8nt][64l][8e] 8192B
#define WS_P3 73728    // GEMM3 B: W0    [2nt][4t][64l][8e]  8192B
#define WS_T  81920    // tables f32: W0[:,16],W0[:,17],W0[:,18],b0,b1,Wo (6x128) 3072B
#define WS_BYTES 84992

// Same-wave DS RAW ordering: LDS ops from one wave execute in order, so a
// wave-private bounce needs only COMPILE-TIME ordering (no runtime drain).
// The compiler still auto-inserts lgkmcnt(N) before uses of ds_read results.
#define DS_ORDER() asm volatile("" ::: "memory")

// ---------------------------------------------------------------------------
// Prep: pack weights into MFMA fragment order.
// Frag maps (16x16x32, c=l&15, g=l>>4):
//   A[row][k]  : lane l elem e -> A[c][8g+e]
//   B[k][col]  : lane l elem e -> B[8g+e][c]
//   D[row][col]: lane l reg  r -> D[4g+r][c]
// ---------------------------------------------------------------------------
__global__ void pack_weights(const float* __restrict__ W0, const float* __restrict__ b0,
                             const float* __restrict__ W1, const float* __restrict__ b1,
                             const float* __restrict__ Wo, unsigned char* __restrict__ ws) {
    int idx = blockIdx.x * 256 + threadIdx.x;
    f16* p1 = (f16*)(ws + WS_P1);
    f16* p2 = (f16*)(ws + WS_P2);
    f16* p0 = (f16*)(ws + WS_P0);
    f16* p3 = (f16*)(ws + WS_P3);
    float* tb = (float*)(ws + WS_T);
    if (idx < 16384) {                       // PACK1: B=W1T -> elem = W1[c+16nt][8g+e+32t]
        int e = idx & 7, l = (idx >> 3) & 63, t = (idx >> 9) & 3, nt = idx >> 11;
        int c = l & 15, g = l >> 4;
        p1[idx] = (f16)W1[(c + 16*nt)*HDIM + (8*g + e + 32*t)];
    } else if (idx < 32768) {                // PACK2: B=W1  -> elem = W1[8g+e+32t][c+16nt]
        int i = idx - 16384;
        int e = i & 7, l = (i >> 3) & 63, t = (i >> 9) & 3, nt = i >> 11;
        int c = l & 15, g = l >> 4;
        p2[i] = (f16)W1[(8*g + e + 32*t)*HDIM + (c + 16*nt)];
    } else if (idx < 36864) {                // PACK0: B=W0T emb rows (k=d<16 real, else 0)
        int i = idx - 32768;
        int e = i & 7, l = (i >> 3) & 63, nt = i >> 9;
        int c = l & 15, g = l >> 4;
        int d = 8*g + e;
        p0[i] = (d < EDIM) ? (f16)W0[(c + 16*nt)*DIN + d] : (f16)0.f;
    } else if (idx < 40960) {                // PACK3: B=W0 (col=din<19 real, else 0)
        int i = idx - 36864;
        int e = i & 7, l = (i >> 3) & 63, t = (i >> 9) & 3, nt = i >> 11;
        int c = l & 15, g = l >> 4;
        int din = c + 16*nt;
        p3[i] = (din < DIN) ? (f16)W0[(8*g + e + 32*t)*DIN + din] : (f16)0.f;
    } else if (idx < 41728) {                // tables
        int i = idx - 40960;
        int j = i & 127, sel = i >> 7;
        float v;
        if (sel == 0)      v = W0[j*DIN + 16];
        else if (sel == 1) v = W0[j*DIN + 17];
        else if (sel == 2) v = W0[j*DIN + 18];
        else if (sel == 3) v = b0[j];
        else if (sel == 4) v = b1[j];
        else               v = Wo[j];
        tb[i] = v;
    }
}

// ---------------------------------------------------------------------------
// FINAL champion (r14, 112.5 us). Persistent fused kernel. 256 blocks
// (1/CU) x 768 thr (12 waves = 3 waves/SIMD). ALL packs in LDS.
// LDS = 133376 B. Session ledger of closed paths:
//  - >=4 waves/SIMD implied (hint>=4 / 1024-thr): VGPR collapses to 64,
//    spills (r3/r6/r8).
//  - L2-streamed MFMA B-operands: latency poison at low occupancy (r7).
//  - Reg-hoisted B-frags / gather prefetch / waves_per_eu(1,3): allocator
//    pins 84 VGPR at 768 thr and spills any added live state (r12/r15/r16).
//  - 2-batch in-wave ILP at 8 waves: loses to 12-wave TLP (r11).
// ---------------------------------------------------------------------------
__global__ __launch_bounds__(768, 1)
void sdf_mfma(const float* __restrict__ pos,
              const float* __restrict__ gridp,
              const unsigned char* __restrict__ ws,
              const float* __restrict__ bo,
              float* __restrict__ out) {
    __shared__ f16 sP1[16384];
    __shared__ f16 sP2[16384];
    __shared__ f16 sP0[4096];
    __shared__ f16 sP3[4096];
    __shared__ float sT[768];
    __shared__ unsigned char sBounce[NWAVE][4352];   // per-wave: 16 rows x 136 f16

    const int tid = threadIdx.x;
    // ---- stage packs to LDS (once per block; 768 threads) ----
    {
        const uint4* src = (const uint4*)ws;
        uint4* d1 = (uint4*)sP1;
        uint4* d2 = (uint4*)sP2;
        uint4* d0 = (uint4*)sP0;
        uint4* d3 = (uint4*)sP3;
        uint4* dt = (uint4*)sT;
#pragma unroll
        for (int i = 0; i < 3; ++i) {
            int k = tid + i * 768;
            if (k < 2048) { d1[k] = src[k]; d2[k] = src[2048 + k]; }
        }
        if (tid < 512) { d0[tid] = src[4096 + tid]; d3[tid] = src[4608 + tid]; }
        if (tid < 192) dt[tid] = src[5120 + tid];
    }
    __syncthreads();

    const int l = tid & 63, w = tid >> 6;
    const int c = l & 15, g = l >> 4;
    const int s = g & 1, q = g >> 1;     // gather: slice s, corner-quad q

    f16* sBW = (f16*)sBounce[w];
    const f16x8* P0 = (const f16x8*)sP0;
    const f16x8* P1 = (const f16x8*)sP1;
    const f16x8* P2 = (const f16x8*)sP2;
    const f16x8* P3 = (const f16x8*)sP3;
    const f32x4 z4 = {0.f, 0.f, 0.f, 0.f};
    const float bov = bo[0];

#pragma unroll 1
    for (int it = 0; it < NITER; ++it) {
        const int pbase = (blockIdx.x * NITER + it) * BATCH + w * 16;
        if (pbase >= NPTS) continue;          // wave-uniform tail skip
        const int pt = pbase + c;

        // ---- trilinear setup for point c (all lanes) ----
        const float px = fmaf(pos[3*pt+0], 0.5f, 0.5f);
        const float py = fmaf(pos[3*pt+1], 0.5f, 0.5f);
        const float pz = fmaf(pos[3*pt+2], 0.5f, 0.5f);
        const float x0 = px*127.f, x1 = py*127.f, x2 = pz*127.f;
        int i0 = (int)floorf(x0); i0 = i0 < 0 ? 0 : (i0 > 126 ? 126 : i0);
        int i1 = (int)floorf(x1); i1 = i1 < 0 ? 0 : (i1 > 126 ? 126 : i1);
        int i2 = (int)floorf(x2); i2 = i2 < 0 ? 0 : (i2 > 126 ? 126 : i2);
        const float f0 = x0 - (float)i0, f1 = x1 - (float)i1, f2 = x2 - (float)i2;
        const float wx1 = f0, wx0 = 1.f - f0;
        const float wy1 = f1, wy0 = 1.f - f1;
        const float wz1 = f2, wz0 = 1.f - f2;
        const float* gb = gridp + (size_t)((i0*RES + i1)*RES + i2)*EDIM;

        // ---- ALL-LANE gather: lane (c,g) loads 4 corners (quad q) of
        //      slice s; halves the serial chain vs 16-lane/8-corner form.
        float w8[8] = {0.f,0.f,0.f,0.f,0.f,0.f,0.f,0.f};
        {
            const float wxq = q ? wx1 : wx0;
#pragma unroll
            for (int j = 0; j < 4; ++j) {
                const float* gp = gb + q*OXs + ((j>>1)&1)*OYs + (j&1)*OZs + 8*s;
                float4 qa = *(const float4*)gp;
                float4 qb = *(const float4*)(gp + 4);
                const float wc = wxq * ((j&2)?wy1:wy0) * ((j&1)?wz1:wz0);
                w8[0] = fmaf(wc, qa.x, w8[0]);  w8[1] = fmaf(wc, qa.y, w8[1]);
                w8[2] = fmaf(wc, qa.z, w8[2]);  w8[3] = fmaf(wc, qa.w, w8[3]);
                w8[4] = fmaf(wc, qb.x, w8[4]);  w8[5] = fmaf(wc, qb.y, w8[5]);
                w8[6] = fmaf(wc, qb.z, w8[6]);  w8[7] = fmaf(wc, qb.w, w8[7]);
            }
        }
        // combine corner-quads: partner lane is lane^32 (g^2)
        f16x8 afe;
#pragma unroll
        for (int m = 0; m < 8; ++m) {
            const float full = w8[m] + __shfl_xor(w8[m], 32);
            afe[m] = (g < 2) ? (f16)full : (f16)0.f;
        }

        // ---- GEMM0: a0 emb part ----
        f32x4 acc[8];
        __builtin_amdgcn_s_setprio(1);
#pragma unroll
        for (int nt = 0; nt < 8; ++nt)
            acc[nt] = __builtin_amdgcn_mfma_f32_16x16x32_f16(afe, P0[nt*64 + l], z4, 0, 0, 0);
        __builtin_amdgcn_s_setprio(0);

        // ---- pos/bias fold (exact fp32), t0 = 30*a0, h1 -> bounce ----
        // pos reload for rows 4g..4g+3: 12 consecutive floats, 16B-aligned
        float rpx[4], rpy[4], rpz[4];
        {
            const float* pp = pos + 3 * (pbase + 4*g);
            const float4 fa = *(const float4*)(pp + 0);
            const float4 fb = *(const float4*)(pp + 4);
            const float4 fc = *(const float4*)(pp + 8);
            rpx[0] = fmaf(fa.x, 0.5f, 0.5f); rpy[0] = fmaf(fa.y, 0.5f, 0.5f); rpz[0] = fmaf(fa.z, 0.5f, 0.5f);
            rpx[1] = fmaf(fa.w, 0.5f, 0.5f); rpy[1] = fmaf(fb.x, 0.5f, 0.5f); rpz[1] = fmaf(fb.y, 0.5f, 0.5f);
            rpx[2] = fmaf(fb.z, 0.5f, 0.5f); rpy[2] = fmaf(fb.w, 0.5f, 0.5f); rpz[2] = fmaf(fc.x, 0.5f, 0.5f);
            rpx[3] = fmaf(fc.y, 0.5f, 0.5f); rpy[3] = fmaf(fc.z, 0.5f, 0.5f); rpz[3] = fmaf(fc.w, 0.5f, 0.5f);
        }
        float t0a[8][4];
#pragma unroll
        for (int nt = 0; nt < 8; ++nt) {
            const int j = c + 16*nt;
            const float t16 = sT[j], t17 = sT[128+j], t18 = sT[256+j], tb0 = sT[384+j];
#pragma unroll
            for (int r = 0; r < 4; ++r) {
                float a0 = acc[nt][r] + tb0;
                a0 = fmaf(rpx[r], t16, a0);
                a0 = fmaf(rpy[r], t17, a0);
                a0 = fmaf(rpz[r], t18, a0);
                const float t0 = 30.f * a0;
                t0a[nt][r] = t0;
                sBW[(4*g + r)*136 + j] = (f16)__sinf(t0);
            }
        }
        DS_ORDER();   // same-wave DS in-order: no runtime drain needed

        // ---- GEMM1: a1 = h1 @ W1T ----
        f16x8 af[4];
#pragma unroll
        for (int t = 0; t < 4; ++t)
            af[t] = *(const f16x8*)&sBW[c*136 + 32*t + 8*g];
        __builtin_amdgcn_s_setprio(1);
#pragma unroll
        for (int nt = 0; nt < 8; ++nt) {
            f32x4 a = z4;
#pragma unroll
            for (int t = 0; t < 4; ++t)
                a = __builtin_amdgcn_mfma_f32_16x16x32_f16(af[t], P1[(nt*4+t)*64 + l], a, 0, 0, 0);
            acc[nt] = a;
        }
        __builtin_amdgcn_s_setprio(0);

        // ---- mid: sdf partial + da1 -> bounce ----
        float sp[4] = {0.f, 0.f, 0.f, 0.f};
#pragma unroll
        for (int nt = 0; nt < 8; ++nt) {
            const int j = c + 16*nt;
            const float b1j = sT[512+j], woj = sT[640+j];
#pragma unroll
            for (int r = 0; r < 4; ++r) {
                const float t1 = 30.f * (acc[nt][r] + b1j);
                sp[r] = fmaf(woj, __sinf(t1), sp[r]);
                sBW[(4*g + r)*136 + j] = (f16)(30.f * woj * __cosf(t1));
            }
        }
        // sdf reduce over c-lanes and store
#pragma unroll
        for (int r = 0; r < 4; ++r) {
            sp[r] += __shfl_xor(sp[r], 1);
            sp[r] += __shfl_xor(sp[r], 2);
            sp[r] += __shfl_xor(sp[r], 4);
            sp[r] += __shfl_xor(sp[r], 8);
        }
        if (c == 0) {
#pragma unroll
            for (int r = 0; r < 4; ++r) out[pbase + 4*g + r] = sp[r] + bov;
        }
        DS_ORDER();

        // ---- hoist grad-combine corner loads (hide latency under GEMM2/3) ----
        float4 ca[2][4];
#pragma unroll
        for (int h = 0; h < 2; ++h) {
            const int cr = 2*g + h;
            const float* gp = gb + ((cr>>2)&1)*OXs + ((cr>>1)&1)*OYs + (cr&1)*OZs;
            ca[h][0] = *(const float4*)gp;
            ca[h][1] = *(const float4*)(gp + 4);
            ca[h][2] = *(const float4*)(gp + 8);
            ca[h][3] = *(const float4*)(gp + 12);
        }

        // ---- GEMM2: dh1 = da1 @ W1 ----
#pragma unroll
        for (int t = 0; t < 4; ++t)
            af[t] = *(const f16x8*)&sBW[c*136 + 32*t + 8*g];
        __builtin_amdgcn_s_setprio(1);
#pragma unroll
        for (int nt = 0; nt < 8; ++nt) {
            f32x4 a = z4;
#pragma unroll
            for (int t = 0; t < 4; ++t)
                a = __builtin_amdgcn_mfma_f32_16x16x32_f16(af[t], P2[(nt*4+t)*64 + l], a, 0, 0, 0);
            acc[nt] = a;
        }
        __builtin_amdgcn_s_setprio(0);

        // ---- da0 = dh1 * 30*cos(t0) -> bounce ----
#pragma unroll
        for (int nt = 0; nt < 8; ++nt) {
            const int k = c + 16*nt;
#pragma unroll
            for (int r = 0; r < 4; ++r) {
                const float da0 = acc[nt][r] * (30.f * __cosf(t0a[nt][r]));
                sBW[(4*g + r)*136 + k] = (f16)da0;
            }
        }
        DS_ORDER();

        // ---- GEMM3: dv = da0 @ W0 ----
#pragma unroll
        for (int t = 0; t < 4; ++t)
            af[t] = *(const f16x8*)&sBW[c*136 + 32*t + 8*g];
        f32x4 d3a = z4, d3b = z4;
        __builtin_amdgcn_s_setprio(1);
#pragma unroll
        for (int t = 0; t < 4; ++t) {
            d3a = __builtin_amdgcn_mfma_f32_16x16x32_f16(af[t], P3[t*64 + l],     d3a, 0, 0, 0);
            d3b = __builtin_amdgcn_mfma_f32_16x16x32_f16(af[t], P3[(4+t)*64 + l], d3b, 0, 0, 0);
        }
        __builtin_amdgcn_s_setprio(0);

        // ---- dv -> LDS (reuse bounce region as fp32 [16][20]) ----
        float* sDV = (float*)sBounce[w];
#pragma unroll
        for (int r = 0; r < 4; ++r) sDV[(4*g + r)*20 + c] = d3a[r];
        if (c < 3) {
#pragma unroll
            for (int r = 0; r < 4; ++r) sDV[(4*g + r)*20 + 16 + c] = d3b[r];
        }
        DS_ORDER();

        // ---- gradient combine: lane (c,g) does corners 2g, 2g+1 of point c ----
        const f32x4 dva = *(const f32x4*)&sDV[c*20 + 0];
        const f32x4 dvb = *(const f32x4*)&sDV[c*20 + 4];
        const f32x4 dvc = *(const f32x4*)&sDV[c*20 + 8];
        const f32x4 dvd = *(const f32x4*)&sDV[c*20 + 12];
        float scv[2];
#pragma unroll
        for (int h = 0; h < 2; ++h) {
            float sdot = ca[h][0].x*dva[0] + ca[h][0].y*dva[1] + ca[h][0].z*dva[2] + ca[h][0].w*dva[3]
                       + ca[h][1].x*dvb[0] + ca[h][1].y*dvb[1] + ca[h][1].z*dvb[2] + ca[h][1].w*dvb[3]
                       + ca[h][2].x*dvc[0] + ca[h][2].y*dvc[1] + ca[h][2].z*dvc[2] + ca[h][2].w*dvc[3]
                       + ca[h][3].x*dvd[0] + ca[h][3].y*dvd[1] + ca[h][3].z*dvd[2] + ca[h][3].w*dvd[3];
            scv[h] = sdot;
        }
        float* sSC = (float*)sBounce[w] + 320;   // 16 x 8 f32
        sSC[c*8 + 2*g]     = scv[0];
        sSC[c*8 + 2*g + 1] = scv[1];
        DS_ORDER();
        if (g == 0) {
            const float* scp = &sSC[c*8];
            const float sc0 = scp[0], sc1 = scp[1], sc2 = scp[2], sc3 = scp[3];
            const float sc4 = scp[4], sc5 = scp[5], sc6 = scp[6], sc7 = scp[7];
            const float gx = 127.f * (wy0*wz0*(sc4-sc0) + wy0*wz1*(sc5-sc1) +
                                      wy1*wz0*(sc6-sc2) + wy1*wz1*(sc7-sc3));
            const float gy = 127.f * (wx0*wz0*(sc2-sc0) + wx0*wz1*(sc3-sc1) +
                                      wx1*wz0*(sc6-sc4) + wx1*wz1*(sc7-sc5));
            const float gz = 127.f * (wx0*wy0*(sc1-sc0) + wx0*wy1*(sc3-sc2) +
                                      wx1*wy0*(sc5-sc4) + wx1*wy1*(sc7-sc6));
            out[NPTS + 3*pt + 0] = gx + sDV[c*20 + 16];
            out[NPTS + 3*pt + 1] = gy + sDV[c*20 + 17];
            out[NPTS + 3*pt + 2] = gz + sDV[c*20 + 18];
        }
        DS_ORDER();   // keep next iteration's writes ordered after these reads
    }
}

// ===========================================================================
// Fallback (round-2 proven VALU path) — used only if ws_size < WS_BYTES.
// ===========================================================================
#define JCHUNK 64
__global__ void transpose_w1(const float* __restrict__ W1, float* __restrict__ W1T) {
    int idx = blockIdx.x * 256 + threadIdx.x;
    if (idx < HDIM * HDIM) {
        int j = idx >> 7, k = idx & 127;
        W1T[k * HDIM + j] = W1[j * HDIM + k];
    }
}
#define LOAD16(gq)                                   \
    float4 q0 = *(const float4*)((gq) + 0);          \
    float4 q1 = *(const float4*)((gq) + 4);          \
    float4 q2 = *(const float4*)((gq) + 8);          \
    float4 q3 = *(const float4*)((gq) + 12);

template<int RS, int CS>
__global__ __launch_bounds__(256, 2)
void sdf_fused(const float* __restrict__ pos, const float* __restrict__ gridp,
               const float* __restrict__ W0, const float* __restrict__ b0,
               const float* __restrict__ W1m, const float* __restrict__ b1,
               const float* __restrict__ Wo, const float* __restrict__ bo,
               float* __restrict__ out) {
    const int i = blockIdx.x * 256 + threadIdx.x;
    if (i >= NPTS) return;
    const float W0S = 30.0f;
    const float px = fmaf(pos[3*i+0], 0.5f, 0.5f);
    const float py = fmaf(pos[3*i+1], 0.5f, 0.5f);
    const float pz = fmaf(pos[3*i+2], 0.5f, 0.5f);
    const float x0 = px*127.f, x1 = py*127.f, x2 = pz*127.f;
    int i0 = (int)floorf(x0); i0 = i0 < 0 ? 0 : (i0 > 126 ? 126 : i0);
    int i1 = (int)floorf(x1); i1 = i1 < 0 ? 0 : (i1 > 126 ? 126 : i1);
    int i2 = (int)floorf(x2); i2 = i2 < 0 ? 0 : (i2 > 126 ? 126 : i2);
    const float f0 = x0-(float)i0, f1 = x1-(float)i1, f2 = x2-(float)i2;
    const float wx1 = f0, wx0 = 1.f-f0, wy1 = f1, wy0 = 1.f-f1, wz1 = f2, wz0 = 1.f-f2;
    const float* gb = gridp + (size_t)((i0*RES+i1)*RES+i2)*EDIM;
    float cw[8];
    cw[0]=wx0*wy0*wz0; cw[1]=wx0*wy0*wz1; cw[2]=wx0*wy1*wz0; cw[3]=wx0*wy1*wz1;
    cw[4]=wx1*wy0*wz0; cw[5]=wx1*wy0*wz1; cw[6]=wx1*wy1*wz0; cw[7]=wx1*wy1*wz1;
    float v[DIN];
#pragma unroll
    for (int e = 0; e < EDIM; ++e) v[e] = 0.f;
#pragma unroll
    for (int cr = 0; cr < 8; ++cr) {
        const float* gq = gb + ((cr>>2)&1)*OXs + ((cr>>1)&1)*OYs + (cr&1)*OZs;
        LOAD16(gq);
        const float wc = cw[cr];
        v[0]=fmaf(wc,q0.x,v[0]); v[1]=fmaf(wc,q0.y,v[1]); v[2]=fmaf(wc,q0.z,v[2]); v[3]=fmaf(wc,q0.w,v[3]);
        v[4]=fmaf(wc,q1.x,v[4]); v[5]=fmaf(wc,q1.y,v[5]); v[6]=fmaf(wc,q1.z,v[6]); v[7]=fmaf(wc,q1.w,v[7]);
        v[8]=fmaf(wc,q2.x,v[8]); v[9]=fmaf(wc,q2.y,v[9]); v[10]=fmaf(wc,q2.z,v[10]); v[11]=fmaf(wc,q2.w,v[11]);
        v[12]=fmaf(wc,q3.x,v[12]); v[13]=fmaf(wc,q3.y,v[13]); v[14]=fmaf(wc,q3.z,v[14]); v[15]=fmaf(wc,q3.w,v[15]);
    }
    v[16]=px; v[17]=py; v[18]=pz;
    float dv[DIN];
#pragma unroll
    for (int m = 0; m < DIN; ++m) dv[m] = 0.f;
    float sdf = bo[0];
#pragma unroll 1
    for (int cch = 0; cch < HDIM/JCHUNK; ++cch) {
        const int j0 = cch * JCHUNK;
        float a1c[JCHUNK];
#pragma unroll
        for (int jj = 0; jj < JCHUNK; ++jj) a1c[jj] = 0.f;
#pragma unroll 1
    for (int k = 0; k < HDIM; ++k) {
            float a0 = b0[k];
            const float* w0r = W0 + k*DIN;
#pragma unroll
            for (int m = 0; m < DIN; ++m) a0 = fmaf(w0r[m], v[m], a0);
            const float h1 = __sinf(W0S*a0);
            const float* wr = W1m + k*RS + j0*CS;
#pragma unroll
            for (int jj = 0; jj < JCHUNK; ++jj) a1c[jj] = fmaf(wr[jj*CS], h1, a1c[jj]);
        }
#pragma unroll
        for (int jj = 0; jj < JCHUNK; ++jj) {
            const float t = W0S*(a1c[jj] + b1[j0+jj]);
            float sv, co; __sincosf(t, &sv, &co);
            const float wo = Wo[j0+jj];
            sdf = fmaf(wo, sv, sdf);
            a1c[jj] = (W0S*wo)*co;
        }
#pragma unroll 1
        for (int k = 0; k < HDIM; ++k) {
            const float* wr = W1m + k*RS + j0*CS;
            float s0=0.f,s1=0.f,s2=0.f,s3=0.f;
#pragma unroll
            for (int jj = 0; jj < JCHUNK; jj += 4) {
                s0 = fmaf(wr[(jj+0)*CS], a1c[jj+0], s0);
                s1 = fmaf(wr[(jj+1)*CS], a1c[jj+1], s1);
                s2 = fmaf(wr[(jj+2)*CS], a1c[jj+2], s2);
                s3 = fmaf(wr[(jj+3)*CS], a1c[jj+3], s3);
            }
            const float dh1 = (s0+s1)+(s2+s3);
            float a0 = b0[k];
            const float* w0r = W0 + k*DIN;
#pragma unroll
            for (int m = 0; m < DIN; ++m) a0 = fmaf(w0r[m], v[m], a0);
            const float da0 = dh1 * W0S * __cosf(W0S*a0);
#pragma unroll
            for (int m = 0; m < DIN; ++m) dv[m] = fmaf(w0r[m], da0, dv[m]);
        }
    }
    float sc[8];
#pragma unroll
    for (int cr = 0; cr < 8; ++cr) {
        const float* gq = gb + ((cr>>2)&1)*OXs + ((cr>>1)&1)*OYs + (cr&1)*OZs;
        LOAD16(gq);
        float t0 = q0.x*dv[0]+q0.y*dv[1]+q0.z*dv[2]+q0.w*dv[3];
        float t1 = q1.x*dv[4]+q1.y*dv[5]+q1.z*dv[6]+q1.w*dv[7];
        float t2 = q2.x*dv[8]+q2.y*dv[9]+q2.z*dv[10]+q2.w*dv[11];
        float t3 = q3.x*dv[12]+q3.y*dv[13]+q3.z*dv[14]+q3.w*dv[15];
        sc[cr] = (t0+t1)+(t2+t3);
    }
    const float gx = 127.f*(wy0*wz0*(sc[4]-sc[0]) + wy0*wz1*(sc[5]-sc[1]) + wy1*wz0*(sc[6]-sc[2]) + wy1*wz1*(sc[7]-sc[3]));
    const float gy = 127.f*(wx0*wz0*(sc[2]-sc[0]) + wx0*wz1*(sc[3]-sc[1]) + wx1*wz0*(sc[6]-sc[4]) + wx1*wz1*(sc[7]-sc[5]));
    const float gz = 127.f*(wx0*wy0*(sc[1]-sc[0]) + wx0*wy1*(sc[3]-sc[2]) + wx1*wy0*(sc[5]-sc[4]) + wx1*wy1*(sc[7]-sc[6]));
    out[i] = sdf;
    out[NPTS + 3*i + 0] = gx + dv[16];
    out[NPTS + 3*i + 1] = gy + dv[17];
    out[NPTS + 3*i + 2] = gz + dv[18];
}

// ---------------------------------------------------------------------------
extern "C" void kernel_launch(void* const* d_in, const int* in_sizes, int n_in,
                              void* d_out, int out_size, void* d_ws, size_t ws_size,
                              hipStream_t stream) {
    const float* pos  = (const float*)d_in[0];
    const float* grid = (const float*)d_in[1];
    const float* W0   = (const float*)d_in[2];
    const float* b0   = (const float*)d_in[3];
    const float* W1   = (const float*)d_in[4];
    const float* b1   = (const float*)d_in[5];
    const float* Wo   = (const float*)d_in[6];
    const float* bo   = (const float*)d_in[7];
    float* out = (float*)d_out;

    if (ws_size >= (size_t)WS_BYTES) {
        pack_weights<<<(41728 + 255)/256, 256, 0, stream>>>(W0, b0, W1, b1, Wo, (unsigned char*)d_ws);
        sdf_mfma<<<NBLK, 768, 0, stream>>>(pos, grid, (const unsigned char*)d_ws, bo, out);
    } else if (ws_size >= (size_t)(HDIM*HDIM*sizeof(float))) {
        float* W1T = (float*)d_ws;
        transpose_w1<<<(HDIM*HDIM + 255)/256, 256, 0, stream>>>(W1, W1T);
        sdf_fused<HDIM, 1><<<NPTS/256, 256, 0, stream>>>(pos, grid, W0, b0, W1T, b1, Wo, bo, out);
    } else {
        sdf_fused<1, HDIM><<<NPTS/256, 256, 0, stream>>>(pos, grid, W0, b0, W1, b1, Wo, bo, out);
    }
}